// Round 1
// baseline (176.863 us; speedup 1.0000x reference)
//
#include <hip/hip_runtime.h>
#include <hip/hip_bf16.h>

#define GLOBAL_AS __attribute__((address_space(1)))
#define LDS_AS    __attribute__((address_space(3)))

typedef __bf16 bf16x8 __attribute__((ext_vector_type(8)));
typedef float  f32x4  __attribute__((ext_vector_type(4)));

constexpr int BATCH = 8192;           // M
constexpr int IN    = 1024;
constexpr int OUT   = 1024;           // N
constexpr int KDIM  = IN * 4;         // 4096 (4 "powers" per input)
constexpr int BM = 128, BN = 256, BK = 64;
constexpr int NKT  = KDIM / BK;       // 64 K-tiles
constexpr int LDSBUF = 24576;         // ushort elems per LDS buffer: A 8192 + B 16384 (48 KB)

// round-to-nearest-even float -> bf16 bits (inputs finite)
__device__ __forceinline__ unsigned short f2bf(float f) {
    union { float f; unsigned u; } v; v.f = f;
    unsigned r = v.u + 0x7fffu + ((v.u >> 16) & 1u);
    return (unsigned short)(r >> 16);
}
__device__ __forceinline__ unsigned pk(unsigned short a, unsigned short b) {
    return (unsigned)a | ((unsigned)b << 16);
}

// Merged prep: blocks [0,8192) build A_big; blocks [8192,9216) build B_big + be.
// A_big[b, 4i+k] = {silu(x), x, x^2, x^3} bf16.
// B_big[o, 4i+k] = {W[o,i], C[o,i,1..3]} bf16; be[o] = bias[o] + sum_i C[o,i,0].
// UNCHANGED this round (attribution: gemm-only change; prep counters surface next round).
__global__ __launch_bounds__(256) void prep(const float* __restrict__ x,
                                            const float* __restrict__ W,
                                            const float* __restrict__ C,
                                            const float* __restrict__ bias,
                                            unsigned short* __restrict__ Ab,
                                            unsigned short* __restrict__ Bb,
                                            float* __restrict__ be) {
    if (blockIdx.x < 8192) {
        int idx = blockIdx.x * 256 + threadIdx.x;      // 8192*1024/4 threads
        float4 v = reinterpret_cast<const float4*>(x)[idx];
        float e0[4] = {v.x, v.y, v.z, v.w};
        unsigned short o[16];
#pragma unroll
        for (int j = 0; j < 4; ++j) {
            float xv = e0[j];
            float s  = xv / (1.0f + __expf(-xv));
            float x2 = xv * xv;
            o[4*j+0] = f2bf(s);
            o[4*j+1] = f2bf(xv);
            o[4*j+2] = f2bf(x2);
            o[4*j+3] = f2bf(x2 * xv);
        }
        uint4 d0 = make_uint4(pk(o[0],o[1]), pk(o[2],o[3]),   pk(o[4],o[5]),   pk(o[6],o[7]));
        uint4 d1 = make_uint4(pk(o[8],o[9]), pk(o[10],o[11]), pk(o[12],o[13]), pk(o[14],o[15]));
        uint4* dst = reinterpret_cast<uint4*>(Ab) + (size_t)idx * 2;
        dst[0] = d0;
        dst[1] = d1;
    } else {
        const int o = blockIdx.x - 8192, t = threadIdx.x;
        const int i0 = t * 4;
        const float4* c4 = reinterpret_cast<const float4*>(C + ((size_t)o * IN + i0) * 4);
        float4 w4 = *reinterpret_cast<const float4*>(W + (size_t)o * IN + i0);
        float wv[4] = {w4.x, w4.y, w4.z, w4.w};
        float s = 0.f;
        unsigned d[8];
#pragma unroll
        for (int j = 0; j < 4; ++j) {
            float4 c = c4[j];
            s += c.x;                                  // x^0 term -> bias
            d[2*j]   = pk(f2bf(wv[j]), f2bf(c.y));
            d[2*j+1] = pk(f2bf(c.z),   f2bf(c.w));
        }
        uint4* dst = reinterpret_cast<uint4*>(Bb + (size_t)o * KDIM + i0 * 4);
        dst[0] = make_uint4(d[0], d[1], d[2], d[3]);
        dst[1] = make_uint4(d[4], d[5], d[6], d[7]);
#pragma unroll
        for (int off = 32; off > 0; off >>= 1) s += __shfl_down(s, off, 64);
        __shared__ float red[4];
        if ((t & 63) == 0) red[t >> 6] = s;
        __syncthreads();
        if (t == 0) be[o] = bias[o] + red[0] + red[1] + red[2] + red[3];
    }
}

// C = A_big(8192x4096) * B_big(1024x4096)^T + be.
//
// Phase-interleaved counted-vmcnt schedule (T3+T4+T5 per the catalog):
//  - BM=128 x BN=256, BK=64; grid = 64x4 = 256 blocks (1/CU), 512 thr = 8 waves (2M x 4N),
//    per-wave 64x64 output (acc 4x4 f32x4 = 64 VGPR).
//  - TRIPLE-buffered LDS (3 x 48 KB = 144 KB, dynamic): staging of tile kt+2 is issued
//    during tile kt's two phases, so the per-tile-boundary s_waitcnt vmcnt(6) only ever
//    waits on loads issued a full tile (2 phases, ~1.5k cyc) earlier. vmcnt never drains
//    to 0 in the main loop (only at kt==NKT-2 for the tail).
//  - 2 phases per K-tile: Q0 reads A-half0 (4 ds_read_b128) + all B (8 reads, held in
//    regs across both phases), 16 MFMA; Q1 reads A-half1 (4 reads), 16 MFMA.
//    Each phase: reads -> stage issue -> s_barrier -> lgkmcnt(0) -> setprio(1) MFMAs.
//  - XOR swizzle (chunk ^= row&7) via pre-swizzled global source (linear gload_lds dest),
//    conflict-free ds_read_b128 (balanced 8 chunks x 16 rows per wave access).
//  - XCD swizzle: 32 blocks of each XCD share one bn -> 2 MB B-panel L2-resident.
//
// Slot-lifetime proof sketch (tile t in buf t%3):
//   writes: issued during t-2 (Q0: A0,B0; Q1: A1,B1); landed by end-of-(t-1) vmcnt(6).
//   reads:  phases of tile t only.  next write (tile t+3) issued during t+1 -- after the
//   end-of-tile-t barrier, so no read/overwrite overlap.
__global__ __launch_bounds__(512, 2) void gemm_kan(
        const unsigned short* __restrict__ Ab,
        const unsigned short* __restrict__ Bb,
        const float* __restrict__ be,
        float* __restrict__ out) {
    extern __shared__ unsigned short smem[];   // 3 * 24576 ushorts = 144 KB

    const int t    = threadIdx.x;
    const int l    = blockIdx.x;               // 0..255
    const int xcd  = l & 7;                    // default round-robin XCD assignment
    const int bn   = xcd >> 1;                 // 0..3  (same bn for whole XCD)
    const int bm   = (xcd & 1) * 32 + (l >> 3);// 0..63
    const int lane = t & 63;
    const int wave = t >> 6;                   // 0..7
    const int wr   = wave >> 2;                // 0..1 : M half of wave grid
    const int wc   = wave & 3;                 // 0..3 : N quarter
    const int l15  = lane & 15;
    const int quad = lane >> 4;
    const int x7   = l15 & 7;

    // ---- staging: thread t covers LDS row t>>3, chunk t&7 of each 64-row unit.
    // LDS(row, c) holds global chunk c ^ (row&7)  =>  source chunk = (t&7) ^ (rowT&7).
    const int rowT = t >> 3;                   // 0..63
    const int chT  = (t & 7) ^ (rowT & 7);
    const unsigned short* aS = Ab + (size_t)(bm * BM + rowT) * KDIM + chT * 8;
    const unsigned short* bS = Bb + (size_t)(bn * BN + rowT) * KDIM + chT * 8;

    // ---- ds_read bases (ushort elements)
    const int aRd = (wr * 32 + l15) * 64;            // A region at offset 0
    const int bRd = 8192 + (wc * 64 + l15) * 64;     // B region at offset 8192
    const int ck0 = (quad ^ x7) * 8;                 // kk=0 chunk (swizzled)
    const int ck1 = ((4 + quad) ^ x7) * 8;           // kk=1 chunk

    f32x4 acc[4][4];
    const f32x4 zero = {0.f, 0.f, 0.f, 0.f};
#pragma unroll
    for (int i = 0; i < 4; ++i)
#pragma unroll
        for (int j = 0; j < 4; ++j) acc[i][j] = zero;

#define STAGE_A(tile, buf, h)                                                          \
    __builtin_amdgcn_global_load_lds(                                                  \
        (const GLOBAL_AS void*)(aS + (size_t)(tile) * BK + (size_t)(h) * 64 * KDIM),   \
        (LDS_AS void*)(smem + (buf) * LDSBUF + (h) * 4096 + t * 8), 16, 0, 0)

#define STAGE_B(tile, buf, h) do {                                                     \
    const unsigned short* s_ = bS + (size_t)(tile) * BK + (size_t)(h) * 128 * KDIM;    \
    unsigned short* d_ = smem + (buf) * LDSBUF + 8192 + (h) * 8192 + t * 8;            \
    __builtin_amdgcn_global_load_lds((const GLOBAL_AS void*)s_, (LDS_AS void*)d_,      \
                                     16, 0, 0);                                        \
    __builtin_amdgcn_global_load_lds((const GLOBAL_AS void*)(s_ + (size_t)64 * KDIM),  \
                                     (LDS_AS void*)(d_ + 4096), 16, 0, 0);             \
} while (0)

    // ---- prologue: tile 0 -> buf0 (6 loads), tile 1 -> buf1 (6 loads)
    STAGE_A(0, 0, 0); STAGE_B(0, 0, 0); STAGE_A(0, 0, 1); STAGE_B(0, 0, 1);
    STAGE_A(1, 1, 0); STAGE_B(1, 1, 0); STAGE_A(1, 1, 1); STAGE_B(1, 1, 1);
    asm volatile("s_waitcnt vmcnt(6)" ::: "memory");   // tile0 landed; tile1 in flight
    __builtin_amdgcn_s_barrier();

    int cb = 0;                                        // buffer of current tile
    for (int kt = 0; kt < NKT; ++kt) {
        const unsigned short* sb = smem + cb * LDSBUF;
        const int  nb = (cb >= 1) ? cb - 1 : 2;        // (cb+2)%3 : buffer for tile kt+2
        const bool pf = (kt + 2) < NKT;

        bf16x8 av[2][2], bvv[4][2];

        // ======== phase Q0: A half0 (rows 0..63) + ALL B; compute acc[0..1][*] ========
        av[0][0] = *reinterpret_cast<const bf16x8*>(sb + aRd + ck0);
        av[0][1] = *reinterpret_cast<const bf16x8*>(sb + aRd + ck1);
        av[1][0] = *reinterpret_cast<const bf16x8*>(sb + aRd + 1024 + ck0);
        av[1][1] = *reinterpret_cast<const bf16x8*>(sb + aRd + 1024 + ck1);
#pragma unroll
        for (int ni = 0; ni < 4; ++ni) {
            bvv[ni][0] = *reinterpret_cast<const bf16x8*>(sb + bRd + ni * 1024 + ck0);
            bvv[ni][1] = *reinterpret_cast<const bf16x8*>(sb + bRd + ni * 1024 + ck1);
        }
        if (pf) { STAGE_A(kt + 2, nb, 0); STAGE_B(kt + 2, nb, 0); }   // 3 loads
        __builtin_amdgcn_s_barrier();
        asm volatile("s_waitcnt lgkmcnt(0)" ::: "memory");
        __builtin_amdgcn_sched_barrier(0);
        __builtin_amdgcn_s_setprio(1);
#pragma unroll
        for (int kk = 0; kk < 2; ++kk)
#pragma unroll
            for (int mi = 0; mi < 2; ++mi)
#pragma unroll
                for (int ni = 0; ni < 4; ++ni)
                    acc[mi][ni] = __builtin_amdgcn_mfma_f32_16x16x32_bf16(
                        av[mi][kk], bvv[ni][kk], acc[mi][ni], 0, 0, 0);
        __builtin_amdgcn_s_setprio(0);
        __builtin_amdgcn_s_barrier();

        // ======== phase Q1: A half1 (rows 64..127); B reused from regs; acc[2..3][*] ====
        av[0][0] = *reinterpret_cast<const bf16x8*>(sb + aRd + 4096 + ck0);
        av[0][1] = *reinterpret_cast<const bf16x8*>(sb + aRd + 4096 + ck1);
        av[1][0] = *reinterpret_cast<const bf16x8*>(sb + aRd + 5120 + ck0);
        av[1][1] = *reinterpret_cast<const bf16x8*>(sb + aRd + 5120 + ck1);
        if (pf) { STAGE_A(kt + 2, nb, 1); STAGE_B(kt + 2, nb, 1); }   // 3 loads
        __builtin_amdgcn_s_barrier();
        asm volatile("s_waitcnt lgkmcnt(0)" ::: "memory");
        __builtin_amdgcn_sched_barrier(0);
        __builtin_amdgcn_s_setprio(1);
#pragma unroll
        for (int kk = 0; kk < 2; ++kk)
#pragma unroll
            for (int mi = 0; mi < 2; ++mi)
#pragma unroll
                for (int ni = 0; ni < 4; ++ni)
                    acc[2 + mi][ni] = __builtin_amdgcn_mfma_f32_16x16x32_bf16(
                        av[mi][kk], bvv[ni][kk], acc[2 + mi][ni], 0, 0, 0);
        __builtin_amdgcn_s_setprio(0);

        // ---- tile boundary: ensure tile kt+1 fully landed; keep tile kt+2 in flight.
        if (kt < NKT - 2) {
            asm volatile("s_waitcnt vmcnt(6)" ::: "memory");
            __builtin_amdgcn_s_barrier();
        } else if (kt == NKT - 2) {
            asm volatile("s_waitcnt vmcnt(0)" ::: "memory");   // tail: drain tile 63
            __builtin_amdgcn_s_barrier();
        }
        cb = (cb == 2) ? 0 : cb + 1;
    }

#undef STAGE_A
#undef STAGE_B

    // ---- epilogue: C/D layout col = lane&15, row = quad*4 + reg
    float bev[4];
#pragma unroll
    for (int ni = 0; ni < 4; ++ni)
        bev[ni] = be[bn * BN + wc * 64 + ni * 16 + l15];

#pragma unroll
    for (int mg = 0; mg < 4; ++mg) {
        const int grow = bm * BM + (mg >> 1) * 64 + wr * 32 + (mg & 1) * 16 + quad * 4;
#pragma unroll
        for (int ni = 0; ni < 4; ++ni) {
            const int gcol = bn * BN + wc * 64 + ni * 16 + l15;
            float* po = out + (size_t)grow * OUT + gcol;
#pragma unroll
            for (int r = 0; r < 4; ++r)
                po[(size_t)r * OUT] = acc[mg][ni][r] + bev[ni];
        }
    }
}

extern "C" void kernel_launch(void* const* d_in, const int* in_sizes, int n_in,
                              void* d_out, int out_size, void* d_ws, size_t ws_size,
                              hipStream_t stream) {
    const float* x    = (const float*)d_in[0];   // [8192,1024]
    const float* W    = (const float*)d_in[1];   // [1024,1024]
    const float* C    = (const float*)d_in[2];   // [1024,1024,4]
    const float* bias = (const float*)d_in[3];   // [1024]
    float* out = (float*)d_out;

    unsigned short* Ab = (unsigned short*)d_ws;                    // 64 MB
    unsigned short* Bb = Ab + (size_t)BATCH * KDIM;                // 8 MB
    float*          be = (float*)(Bb + (size_t)OUT * KDIM);        // 4 KB

    constexpr int LDS_BYTES = 3 * LDSBUF * 2;                      // 147456 = 144 KB
    static bool inited = false;
    if (!inited) {
        hipFuncSetAttribute(reinterpret_cast<const void*>(&gemm_kan),
                            hipFuncAttributeMaxDynamicSharedMemorySize, LDS_BYTES);
        inited = true;
    }

    prep<<<dim3(8192 + 1024), dim3(256), 0, stream>>>(x, W, C, bias, Ab, Bb, be);

    gemm_kan<<<dim3(256), dim3(512), LDS_BYTES, stream>>>(Ab, Bb, be, out);
}